// Round 10
// baseline (68.366 us; speedup 1.0000x reference)
//
#include <hip/hip_runtime.h>

#define D_DIM  1024
#define N_TAPS 64
#define L_SEQ  4096
#define B_SZ   4
#define TK     128   // truncated IR length (64 f16 lag-pairs)
#define RT     16    // outputs per thread: acc16 + ring16 = 32 state VGPRs

typedef int i32x4 __attribute__((ext_vector_type(4)));
typedef _Float16 h2f __attribute__((ext_vector_type(2)));

__device__ float
llvm_amdgcn_raw_buffer_load_fp32(i32x4 srsrc, int voffset, int soffset, int aux)
    __asm("llvm.amdgcn.raw.buffer.load.f32");

__device__ inline i32x4 make_srsrc(const void* ptr, unsigned num_bytes) {
    i32x4 r;
    r.x = (int)(unsigned)(unsigned long long)ptr;
    r.y = (int)((unsigned long long)ptr >> 32);   // stride=0
    r.z = (int)num_bytes;                         // bounds in bytes (OOB -> 0)
    r.w = 0x00020000;                             // raw dword descriptor
    return r;
}

#if __has_builtin(__builtin_amdgcn_fdot2)
#define FDOT2(A, B, C) __builtin_amdgcn_fdot2((A), (B), (C), false)
#else
static __device__ inline float fdot2_asm(h2f a, h2f b, float c) {
    float d;
    asm("v_dot2_f32_f16 %0, %1, %2, %3" : "=v"(d) : "v"(a), "v"(b), "v"(c));
    return d;
}
#define FDOT2(A, B, C) fdot2_asm((A), (B), (C))
#endif

// ---------------------------------------------------------------------------
// Stage 1: impulse response via transposed direct-form II; emits PACKED f16
// lag-pairs K2[m][d] = (k[2m], k[2m+1]), m = 0..63. k[0] = h0 (delta term).
// ---------------------------------------------------------------------------
__global__ __launch_bounds__(64) void kinit_kernel(const float* __restrict__ ab,
                                                   const float* __restrict__ h0,
                                                   h2f* __restrict__ K2) {
    const int d    = blockIdx.x;
    const int lane = threadIdx.x;
    const float a  = ab[(size_t)d * N_TAPS + lane];
    const float bc = ab[(size_t)(D_DIM + d) * N_TAPS + lane];

    float kprev = h0[d];            // k[0]
    float s = bc;                   // s_{lane+1}[0] = b_{lane+1}
    for (int t = 1; t < TK; ++t) {
        const float yv = __shfl(s, 0);        // k[t]
        float       sn = __shfl_down(s, 1);
        if (lane == N_TAPS - 1) sn = 0.f;
        if (t & 1) {
            if (lane == 0) {
                h2f p; p.x = (_Float16)kprev; p.y = (_Float16)yv;
                K2[(size_t)(t >> 1) * D_DIM + d] = p;   // pair (k[t-1], k[t])
            }
        } else {
            kprev = yv;
        }
        s = fmaf(-a, yv, sn);
    }
}

// ---------------------------------------------------------------------------
// Stage 2: truncated causal FIR via v_dot2_f32_f16. R9 lesson: inline-asm reg
// pipelining is unschedulable by hipcc (async writeback not modeled) -> back
// to INTRINSIC loads (R7-proven semantics). R7 lesson: RT=32 state (64 regs)
// pushed bulk state into AGPRs (VGPR_Count=44!) with accvgpr round-trips per
// dot2. THIS ROUND: RT=16 -> acc+ring = 32 regs, total demand ~76 VGPR, so
// state and the 3-buffer/2-phase-lookahead load schedule fit in VGPRs.
// SRSRC loads: voffset = d*4 (one VGPR), soffset = t*4096 (SGPR/SALU, free),
// OOB (incl. negative soffset wrap) returns 0 = free causal padding.
// Ring: slot W2[(tau-t0)&15] = P(tau) = (u[tau], u[tau-1]) as f16x2.
// Pair m contributes dot2(K2[m], P(t0+i-2m)) to acc[i].
// ---------------------------------------------------------------------------
#define KLOAD(KB, PB)                                                           \
    { _Pragma("unroll")                                                         \
      for (int j = 0; j < 4; ++j)                                               \
          KB[j] = __builtin_bit_cast(h2f,                                       \
              llvm_amdgcn_raw_buffer_load_fp32(srk, vd4, ((PB) + j) * 4096, 0)); }

#define ULOAD(UB, M0)                                                           \
    { _Pragma("unroll")                                                         \
      for (int j = 0; j < 4; ++j) {                                             \
          UB[2*j]   = llvm_amdgcn_raw_buffer_load_fp32(sru, vd4,                \
                          (t0 - 2 * ((M0) + j) - 2) * 4096, 0);                 \
          UB[2*j+1] = llvm_amdgcn_raw_buffer_load_fp32(sru, vd4,                \
                          (t0 - 2 * ((M0) + j) - 3) * 4096, 0);                 \
      } }

#define COMP(KB, UB, MB)                                                        \
    { _Pragma("unroll")                                                         \
      for (int mm = 0; mm < 4; ++mm) {                                          \
          const int m = (MB) + mm;                 /* static pair index */      \
          const h2f ks = KB[mm];                                                \
          _Pragma("unroll")                                                     \
          for (int i = 0; i < RT; ++i)                                          \
              acc[i] = FDOT2(ks, W2[(i - 2 * m) & (RT - 1)], acc[i]);           \
          const _Float16 h1  = (_Float16)UB[2*mm];      /* u[t0-2m-2] */        \
          const _Float16 h2v = (_Float16)UB[2*mm+1];    /* u[t0-2m-3] */        \
          h2f n1; n1.x = carry; n1.y = h1;              /* P(t0-2m-1) */        \
          h2f n2; n2.x = h1;    n2.y = h2v;             /* P(t0-2m-2) */        \
          W2[(-2 * m - 1) & (RT - 1)] = n1;                                     \
          W2[(-2 * m - 2) & (RT - 1)] = n2;                                     \
          carry = h2v;                                                          \
      } }

__global__ __launch_bounds__(256) void conv_kernel(const float* __restrict__ u,
                                                   const h2f* __restrict__ K2,
                                                   float* __restrict__ y) {
    // XCD-chunked swizzle, t-chunk fastest (R5's 4096-block variant):
    // co-resident blocks share the k-slice and overlapping u-history in L2.
    const int hw  = blockIdx.x + 4 * (blockIdx.y + 256 * blockIdx.z);
    const int lin = (hw & 7) * 512 + (hw >> 3);        // 4096 blocks, %8==0
    const int tch = lin & 255;
    const int b   = (lin >> 8) & 3;
    const int dg  = lin >> 10;
    const int d   = dg * 256 + threadIdx.x;
    const int t0  = tch * RT;

    const i32x4 srk = make_srsrc(K2, (TK / 2) * D_DIM * 4);
    const i32x4 sru = make_srsrc(u + (size_t)b * L_SEQ * D_DIM, L_SEQ * D_DIM * 4);
    const int vd4 = d * 4;

    float acc[RT];
    #pragma unroll
    for (int i = 0; i < RT; ++i) acc[i] = 0.f;

    // Prologue ring: W2[j] = P(t0+j), j=0..15, from 17 scalar loads.
    float pv[RT + 1];
    #pragma unroll
    for (int j = 0; j < RT + 1; ++j)
        pv[j] = llvm_amdgcn_raw_buffer_load_fp32(sru, vd4, (t0 - 1 + j) * 4096, 0);
    _Float16 carry = (_Float16)pv[0];            // u[t0-1]
    h2f W2[RT];
    #pragma unroll
    for (int j = 0; j < RT; ++j) {
        h2f w; w.x = (_Float16)pv[j + 1]; w.y = (_Float16)pv[j];
        W2[j] = w;
    }

    float ub0[8], ub1[8], ub2[8];
    h2f   kb0[4], kb1[4], kb2[4];
    KLOAD(kb0, 0)  KLOAD(kb1, 4)
    ULOAD(ub0, 0)  ULOAD(ub1, 4)

    // 16 phases x 4 pairs = 64 pairs (TK=128 lags); 3-buffer, 2-phase-ahead.
    // Tail prefetches: k goes OOB->0, u reads unused history. Harmless.
    KLOAD(kb2,  8)  ULOAD(ub2,  8)  COMP(kb0, ub0,  0)   // p0
    KLOAD(kb0, 12)  ULOAD(ub0, 12)  COMP(kb1, ub1,  4)   // p1
    KLOAD(kb1, 16)  ULOAD(ub1, 16)  COMP(kb2, ub2,  8)   // p2
    KLOAD(kb2, 20)  ULOAD(ub2, 20)  COMP(kb0, ub0, 12)   // p3
    KLOAD(kb0, 24)  ULOAD(ub0, 24)  COMP(kb1, ub1, 16)   // p4
    KLOAD(kb1, 28)  ULOAD(ub1, 28)  COMP(kb2, ub2, 20)   // p5
    KLOAD(kb2, 32)  ULOAD(ub2, 32)  COMP(kb0, ub0, 24)   // p6
    KLOAD(kb0, 36)  ULOAD(ub0, 36)  COMP(kb1, ub1, 28)   // p7
    KLOAD(kb1, 40)  ULOAD(ub1, 40)  COMP(kb2, ub2, 32)   // p8
    KLOAD(kb2, 44)  ULOAD(ub2, 44)  COMP(kb0, ub0, 36)   // p9
    KLOAD(kb0, 48)  ULOAD(ub0, 48)  COMP(kb1, ub1, 40)   // p10
    KLOAD(kb1, 52)  ULOAD(ub1, 52)  COMP(kb2, ub2, 44)   // p11
    KLOAD(kb2, 56)  ULOAD(ub2, 56)  COMP(kb0, ub0, 48)   // p12
    KLOAD(kb0, 60)  ULOAD(ub0, 60)  COMP(kb1, ub1, 52)   // p13
                                    COMP(kb2, ub2, 56)   // p14
                                    COMP(kb0, ub0, 60)   // p15

    float* __restrict__ yp = y + ((size_t)b * L_SEQ + t0) * D_DIM + d;
    #pragma unroll
    for (int i = 0; i < RT; ++i) yp[(size_t)i * D_DIM] = acc[i];
}

extern "C" void kernel_launch(void* const* d_in, const int* in_sizes, int n_in,
                              void* d_out, int out_size, void* d_ws, size_t ws_size,
                              hipStream_t stream) {
    const float* u  = (const float*)d_in[0];   // (4, 4096, 1024) f32
    const float* ab = (const float*)d_in[1];   // (2048, 64)      f32
    const float* h0 = (const float*)d_in[2];   // (1024,)         f32
    float* y  = (float*)d_out;                 // (4, 4096, 1024) f32
    h2f*   K2 = (h2f*)d_ws;                    // 64 pairs x 1024 ch x 4B = 256 KB

    kinit_kernel<<<dim3(D_DIM), dim3(64), 0, stream>>>(ab, h0, K2);
    conv_kernel<<<dim3(D_DIM / 256, L_SEQ / RT, B_SZ), dim3(256), 0, stream>>>(u, K2, y);
}

// Round 11
// 63.226 us; speedup vs baseline: 1.0813x; 1.0813x over previous
//
#include <hip/hip_runtime.h>

#define D_DIM  1024
#define N_TAPS 64
#define L_SEQ  4096
#define B_SZ   4
#define TK     128   // truncated IR length (64 f16 lag-pairs)
#define RT     32    // outputs per thread (packed ring window depth)

typedef int i32x4 __attribute__((ext_vector_type(4)));
typedef _Float16 h2f __attribute__((ext_vector_type(2)));

__device__ float
llvm_amdgcn_raw_buffer_load_fp32(i32x4 srsrc, int voffset, int soffset, int aux)
    __asm("llvm.amdgcn.raw.buffer.load.f32");

__device__ inline i32x4 make_srsrc(const void* ptr, unsigned num_bytes) {
    i32x4 r;
    r.x = (int)(unsigned)(unsigned long long)ptr;
    r.y = (int)((unsigned long long)ptr >> 32);   // stride=0
    r.z = (int)num_bytes;                         // bounds in bytes (OOB -> 0)
    r.w = 0x00020000;                             // raw dword descriptor
    return r;
}

#if __has_builtin(__builtin_amdgcn_fdot2)
#define FDOT2(A, B, C) __builtin_amdgcn_fdot2((A), (B), (C), false)
#else
static __device__ inline float fdot2_asm(h2f a, h2f b, float c) {
    float d;
    asm("v_dot2_f32_f16 %0, %1, %2, %3" : "=v"(d) : "v"(a), "v"(b), "v"(c));
    return d;
}
#define FDOT2(A, B, C) fdot2_asm((A), (B), (C))
#endif

// ---------------------------------------------------------------------------
// Stage 1: impulse response via transposed direct-form II; emits PACKED f16
// lag-pairs K2[m][d] = (k[2m], k[2m+1]), m = 0..63. k[0] = h0 (delta term).
// ---------------------------------------------------------------------------
__global__ __launch_bounds__(64) void kinit_kernel(const float* __restrict__ ab,
                                                   const float* __restrict__ h0,
                                                   h2f* __restrict__ K2) {
    const int d    = blockIdx.x;
    const int lane = threadIdx.x;
    const float a  = ab[(size_t)d * N_TAPS + lane];
    const float bc = ab[(size_t)(D_DIM + d) * N_TAPS + lane];

    float kprev = h0[d];            // k[0]
    float s = bc;                   // s_{lane+1}[0] = b_{lane+1}
    for (int t = 1; t < TK; ++t) {
        const float yv = __shfl(s, 0);        // k[t]
        float       sn = __shfl_down(s, 1);
        if (lane == N_TAPS - 1) sn = 0.f;
        if (t & 1) {
            if (lane == 0) {
                h2f p; p.x = (_Float16)kprev; p.y = (_Float16)yv;
                K2[(size_t)(t >> 1) * D_DIM + d] = p;   // pair (k[t-1], k[t])
            }
        } else {
            kprev = yv;
        }
        s = fmaf(-a, yv, sn);
    }
}

// ---------------------------------------------------------------------------
// Stage 2: truncated causal FIR via v_dot2_f32_f16 (2 MACs/lane/cy, f32 acc).
// R10 root-cause: with no launch_bounds, hipcc minimizes VGPRs for max
// occupancy (R5:76, R7:44, R10:32!), forcing state into AGPRs (accvgpr
// round-trips) and sinking all prefetch loads to their uses -> latency-bound.
// Forced (256,4)/(256,8) CAPPED below demand -> spills (R4/R6).
// THIS ROUND: __launch_bounds__(256, 2) -> VGPR cap 256 >> ~130 demand:
// the allocator may hold acc[32]+W2[32]+3x12 prefetch buffers in VGPRs and
// hoist loads 2 phases (~1000 cy) ahead of use. dot2 issue wall = 13.7 us.
// SRSRC loads: voffset=d*4 (one VGPR), soffset=t*4096 (SGPR/SALU, free);
// OOB (incl. negative soffset wrap) returns 0 = free causal padding.
// Ring: slot W2[(tau-t0)&31] = P(tau) = (u[tau], u[tau-1]) as f16x2.
// ---------------------------------------------------------------------------
#define KLOAD(KB, PB)                                                           \
    { _Pragma("unroll")                                                         \
      for (int j = 0; j < 4; ++j)                                               \
          KB[j] = __builtin_bit_cast(h2f,                                       \
              llvm_amdgcn_raw_buffer_load_fp32(srk, vd4, ((PB) + j) * 4096, 0)); }

#define ULOAD(UB, M0)                                                           \
    { _Pragma("unroll")                                                         \
      for (int j = 0; j < 4; ++j) {                                             \
          UB[2*j]   = llvm_amdgcn_raw_buffer_load_fp32(sru, vd4,                \
                          (t0 - 2 * ((M0) + j) - 2) * 4096, 0);                 \
          UB[2*j+1] = llvm_amdgcn_raw_buffer_load_fp32(sru, vd4,                \
                          (t0 - 2 * ((M0) + j) - 3) * 4096, 0);                 \
      } }

#define COMP(KB, UB, MB)                                                        \
    { _Pragma("unroll")                                                         \
      for (int mm = 0; mm < 4; ++mm) {                                          \
          const int m = (MB) + mm;                 /* static pair index */      \
          const h2f ks = KB[mm];                                                \
          _Pragma("unroll")                                                     \
          for (int i = 0; i < RT; ++i)                                          \
              acc[i] = FDOT2(ks, W2[(i - 2 * m) & (RT - 1)], acc[i]);           \
          const _Float16 h1  = (_Float16)UB[2*mm];      /* u[t0-2m-2] */        \
          const _Float16 h2v = (_Float16)UB[2*mm+1];    /* u[t0-2m-3] */        \
          h2f n1; n1.x = carry; n1.y = h1;              /* P(t0-2m-1) */        \
          h2f n2; n2.x = h1;    n2.y = h2v;             /* P(t0-2m-2) */        \
          W2[(-2 * m - 1) & (RT - 1)] = n1;                                     \
          W2[(-2 * m - 2) & (RT - 1)] = n2;                                     \
          carry = h2v;                                                          \
      } }

__global__ __launch_bounds__(256, 2) void conv_kernel(const float* __restrict__ u,
                                                      const h2f* __restrict__ K2,
                                                      float* __restrict__ y) {
    // XCD-chunked swizzle, t-chunk fastest (R5/R7).
    const int hw  = blockIdx.x + 4 * (blockIdx.y + 128 * blockIdx.z);
    const int lin = (hw & 7) * 256 + (hw >> 3);
    const int d   = (lin & 3) * 256 + threadIdx.x;
    const int t0  = ((lin >> 2) & 127) * RT;
    const int b   = lin >> 9;

    const i32x4 srk = make_srsrc(K2, (TK / 2) * D_DIM * 4);
    const i32x4 sru = make_srsrc(u + (size_t)b * L_SEQ * D_DIM, L_SEQ * D_DIM * 4);
    const int vd4 = d * 4;

    float acc[RT];
    #pragma unroll
    for (int i = 0; i < RT; ++i) acc[i] = 0.f;

    // Prologue ring: W2[j] = P(t0+j) from 33 scalar loads (t0-1 .. t0+31).
    float pv[RT + 1];
    #pragma unroll
    for (int j = 0; j < RT + 1; ++j)
        pv[j] = llvm_amdgcn_raw_buffer_load_fp32(sru, vd4, (t0 - 1 + j) * 4096, 0);
    _Float16 carry = (_Float16)pv[0];            // u[t0-1]
    h2f W2[RT];
    #pragma unroll
    for (int j = 0; j < RT; ++j) {
        h2f w; w.x = (_Float16)pv[j + 1]; w.y = (_Float16)pv[j];
        W2[j] = w;
    }

    float ub0[8], ub1[8], ub2[8];
    h2f   kb0[4], kb1[4], kb2[4];
    KLOAD(kb0, 0)  KLOAD(kb1, 4)
    ULOAD(ub0, 0)  ULOAD(ub1, 4)

    // 16 phases x 4 pairs = 64 pairs (TK=128 lags); 3-buffer, 2-phase-ahead.
    // Tail prefetches: k goes OOB->0, u reads unused history. Harmless.
    KLOAD(kb2,  8)  ULOAD(ub2,  8)  COMP(kb0, ub0,  0)   // p0
    KLOAD(kb0, 12)  ULOAD(ub0, 12)  COMP(kb1, ub1,  4)   // p1
    KLOAD(kb1, 16)  ULOAD(ub1, 16)  COMP(kb2, ub2,  8)   // p2
    KLOAD(kb2, 20)  ULOAD(ub2, 20)  COMP(kb0, ub0, 12)   // p3
    KLOAD(kb0, 24)  ULOAD(ub0, 24)  COMP(kb1, ub1, 16)   // p4
    KLOAD(kb1, 28)  ULOAD(ub1, 28)  COMP(kb2, ub2, 20)   // p5
    KLOAD(kb2, 32)  ULOAD(ub2, 32)  COMP(kb0, ub0, 24)   // p6
    KLOAD(kb0, 36)  ULOAD(ub0, 36)  COMP(kb1, ub1, 28)   // p7
    KLOAD(kb1, 40)  ULOAD(ub1, 40)  COMP(kb2, ub2, 32)   // p8
    KLOAD(kb2, 44)  ULOAD(ub2, 44)  COMP(kb0, ub0, 36)   // p9
    KLOAD(kb0, 48)  ULOAD(ub0, 48)  COMP(kb1, ub1, 40)   // p10
    KLOAD(kb1, 52)  ULOAD(ub1, 52)  COMP(kb2, ub2, 44)   // p11
    KLOAD(kb2, 56)  ULOAD(ub2, 56)  COMP(kb0, ub0, 48)   // p12
    KLOAD(kb0, 60)  ULOAD(ub0, 60)  COMP(kb1, ub1, 52)   // p13
                                    COMP(kb2, ub2, 56)   // p14
                                    COMP(kb0, ub0, 60)   // p15

    float* __restrict__ yp = y + ((size_t)b * L_SEQ + t0) * D_DIM + d;
    #pragma unroll
    for (int i = 0; i < RT; ++i) yp[(size_t)i * D_DIM] = acc[i];
}

extern "C" void kernel_launch(void* const* d_in, const int* in_sizes, int n_in,
                              void* d_out, int out_size, void* d_ws, size_t ws_size,
                              hipStream_t stream) {
    const float* u  = (const float*)d_in[0];   // (4, 4096, 1024) f32
    const float* ab = (const float*)d_in[1];   // (2048, 64)      f32
    const float* h0 = (const float*)d_in[2];   // (1024,)         f32
    float* y  = (float*)d_out;                 // (4, 4096, 1024) f32
    h2f*   K2 = (h2f*)d_ws;                    // 64 pairs x 1024 ch x 4B = 256 KB

    kinit_kernel<<<dim3(D_DIM), dim3(64), 0, stream>>>(ab, h0, K2);
    conv_kernel<<<dim3(D_DIM / 256, L_SEQ / RT, B_SZ), dim3(256), 0, stream>>>(u, K2, y);
}

// Round 12
// 63.078 us; speedup vs baseline: 1.0838x; 1.0023x over previous
//
#include <hip/hip_runtime.h>

#define D_DIM  1024
#define N_TAPS 64
#define L_SEQ  4096
#define B_SZ   4
#define TK     128   // truncated IR length (64 f16 lag-pairs)
#define RT     32    // outputs per thread (packed ring window depth)

typedef int i32x4 __attribute__((ext_vector_type(4)));
typedef _Float16 h2f __attribute__((ext_vector_type(2)));

__device__ float
llvm_amdgcn_raw_buffer_load_fp32(i32x4 srsrc, int voffset, int soffset, int aux)
    __asm("llvm.amdgcn.raw.buffer.load.f32");

__device__ inline i32x4 make_srsrc(const void* ptr, unsigned num_bytes) {
    i32x4 r;
    r.x = (int)(unsigned)(unsigned long long)ptr;
    r.y = (int)((unsigned long long)ptr >> 32);   // stride=0
    r.z = (int)num_bytes;                         // bounds in bytes (OOB -> 0)
    r.w = 0x00020000;                             // raw dword descriptor
    return r;
}

#if __has_builtin(__builtin_amdgcn_fdot2)
#define FDOT2(A, B, C) __builtin_amdgcn_fdot2((A), (B), (C), false)
#else
static __device__ inline float fdot2_asm(h2f a, h2f b, float c) {
    float d;
    asm("v_dot2_f32_f16 %0, %1, %2, %3" : "=v"(d) : "v"(a), "v"(b), "v"(c));
    return d;
}
#define FDOT2(A, B, C) fdot2_asm((A), (B), (C))
#endif

// ---------------------------------------------------------------------------
// Stage 1: impulse response via transposed direct-form II; emits PACKED f16
// lag-pairs K2[m][d] = (k[2m], k[2m+1]), m = 0..63. k[0] = h0 (delta term).
// ---------------------------------------------------------------------------
__global__ __launch_bounds__(64) void kinit_kernel(const float* __restrict__ ab,
                                                   const float* __restrict__ h0,
                                                   h2f* __restrict__ K2) {
    const int d    = blockIdx.x;
    const int lane = threadIdx.x;
    const float a  = ab[(size_t)d * N_TAPS + lane];
    const float bc = ab[(size_t)(D_DIM + d) * N_TAPS + lane];

    float kprev = h0[d];            // k[0]
    float s = bc;                   // s_{lane+1}[0] = b_{lane+1}
    for (int t = 1; t < TK; ++t) {
        const float yv = __shfl(s, 0);        // k[t]
        float       sn = __shfl_down(s, 1);
        if (lane == N_TAPS - 1) sn = 0.f;
        if (t & 1) {
            if (lane == 0) {
                h2f p; p.x = (_Float16)kprev; p.y = (_Float16)yv;
                K2[(size_t)(t >> 1) * D_DIM + d] = p;   // pair (k[t-1], k[t])
            }
        } else {
            kprev = yv;
        }
        s = fmaf(-a, yv, sn);
    }
}

// ---------------------------------------------------------------------------
// Stage 2: truncated causal FIR via v_dot2_f32_f16 (2 MACs/lane/cy, f32 acc).
// R11 post-mortem: __launch_bounds__(...,2) only sets the occupancy MINIMUM;
// the allocator's objective stays "maximize occupancy", so it kept arch-VGPR
// at 44, parked state in AGPRs (accvgpr round-trips ~= 2x VALU work) and sank
// all prefetch loads to their uses (~50% stall; R10-vs-R11 showed more waves
// do NOT raise VALUBusy -> allocator, not TLP, is binding).
// THIS ROUND: amdgpu_waves_per_eu(2,2) pins the occupancy TARGET to 2
// waves/EU -> 256-VGPR budget is usable; allocator can keep acc[32]+W2[32]+
// 3x12 prefetch buffers in VGPRs and hoist loads ~2 phases (~1000 cy) ahead.
// SRSRC loads: voffset=d*4 (one VGPR), soffset=t*4096 (SGPR/SALU, free);
// OOB (incl. negative soffset wrap) returns 0 = free causal padding.
// Ring: slot W2[(tau-t0)&31] = P(tau) = (u[tau], u[tau-1]) as f16x2.
// ---------------------------------------------------------------------------
#define KLOAD(KB, PB)                                                           \
    { _Pragma("unroll")                                                         \
      for (int j = 0; j < 4; ++j)                                               \
          KB[j] = __builtin_bit_cast(h2f,                                       \
              llvm_amdgcn_raw_buffer_load_fp32(srk, vd4, ((PB) + j) * 4096, 0)); }

#define ULOAD(UB, M0)                                                           \
    { _Pragma("unroll")                                                         \
      for (int j = 0; j < 4; ++j) {                                             \
          UB[2*j]   = llvm_amdgcn_raw_buffer_load_fp32(sru, vd4,                \
                          (t0 - 2 * ((M0) + j) - 2) * 4096, 0);                 \
          UB[2*j+1] = llvm_amdgcn_raw_buffer_load_fp32(sru, vd4,                \
                          (t0 - 2 * ((M0) + j) - 3) * 4096, 0);                 \
      } }

#define COMP(KB, UB, MB)                                                        \
    { _Pragma("unroll")                                                         \
      for (int mm = 0; mm < 4; ++mm) {                                          \
          const int m = (MB) + mm;                 /* static pair index */      \
          const h2f ks = KB[mm];                                                \
          _Pragma("unroll")                                                     \
          for (int i = 0; i < RT; ++i)                                          \
              acc[i] = FDOT2(ks, W2[(i - 2 * m) & (RT - 1)], acc[i]);           \
          const _Float16 h1  = (_Float16)UB[2*mm];      /* u[t0-2m-2] */        \
          const _Float16 h2v = (_Float16)UB[2*mm+1];    /* u[t0-2m-3] */        \
          h2f n1; n1.x = carry; n1.y = h1;              /* P(t0-2m-1) */        \
          h2f n2; n2.x = h1;    n2.y = h2v;             /* P(t0-2m-2) */        \
          W2[(-2 * m - 1) & (RT - 1)] = n1;                                     \
          W2[(-2 * m - 2) & (RT - 1)] = n2;                                     \
          carry = h2v;                                                          \
      } }

__global__ __launch_bounds__(256)
__attribute__((amdgpu_waves_per_eu(2, 2)))
void conv_kernel(const float* __restrict__ u,
                 const h2f* __restrict__ K2,
                 float* __restrict__ y) {
    // XCD-chunked swizzle, t-chunk fastest (R5/R7).
    const int hw  = blockIdx.x + 4 * (blockIdx.y + 128 * blockIdx.z);
    const int lin = (hw & 7) * 256 + (hw >> 3);
    const int d   = (lin & 3) * 256 + threadIdx.x;
    const int t0  = ((lin >> 2) & 127) * RT;
    const int b   = lin >> 9;

    const i32x4 srk = make_srsrc(K2, (TK / 2) * D_DIM * 4);
    const i32x4 sru = make_srsrc(u + (size_t)b * L_SEQ * D_DIM, L_SEQ * D_DIM * 4);
    const int vd4 = d * 4;

    float acc[RT];
    #pragma unroll
    for (int i = 0; i < RT; ++i) acc[i] = 0.f;

    // Prologue ring: W2[j] = P(t0+j) from 33 scalar loads (t0-1 .. t0+31).
    float pv[RT + 1];
    #pragma unroll
    for (int j = 0; j < RT + 1; ++j)
        pv[j] = llvm_amdgcn_raw_buffer_load_fp32(sru, vd4, (t0 - 1 + j) * 4096, 0);
    _Float16 carry = (_Float16)pv[0];            // u[t0-1]
    h2f W2[RT];
    #pragma unroll
    for (int j = 0; j < RT; ++j) {
        h2f w; w.x = (_Float16)pv[j + 1]; w.y = (_Float16)pv[j];
        W2[j] = w;
    }

    float ub0[8], ub1[8], ub2[8];
    h2f   kb0[4], kb1[4], kb2[4];
    KLOAD(kb0, 0)  KLOAD(kb1, 4)
    ULOAD(ub0, 0)  ULOAD(ub1, 4)

    // 16 phases x 4 pairs = 64 pairs (TK=128 lags); 3-buffer, 2-phase-ahead.
    // Tail prefetches: k goes OOB->0, u reads unused history. Harmless.
    KLOAD(kb2,  8)  ULOAD(ub2,  8)  COMP(kb0, ub0,  0)   // p0
    KLOAD(kb0, 12)  ULOAD(ub0, 12)  COMP(kb1, ub1,  4)   // p1
    KLOAD(kb1, 16)  ULOAD(ub1, 16)  COMP(kb2, ub2,  8)   // p2
    KLOAD(kb2, 20)  ULOAD(ub2, 20)  COMP(kb0, ub0, 12)   // p3
    KLOAD(kb0, 24)  ULOAD(ub0, 24)  COMP(kb1, ub1, 16)   // p4
    KLOAD(kb1, 28)  ULOAD(ub1, 28)  COMP(kb2, ub2, 20)   // p5
    KLOAD(kb2, 32)  ULOAD(ub2, 32)  COMP(kb0, ub0, 24)   // p6
    KLOAD(kb0, 36)  ULOAD(ub0, 36)  COMP(kb1, ub1, 28)   // p7
    KLOAD(kb1, 40)  ULOAD(ub1, 40)  COMP(kb2, ub2, 32)   // p8
    KLOAD(kb2, 44)  ULOAD(ub2, 44)  COMP(kb0, ub0, 36)   // p9
    KLOAD(kb0, 48)  ULOAD(ub0, 48)  COMP(kb1, ub1, 40)   // p10
    KLOAD(kb1, 52)  ULOAD(ub1, 52)  COMP(kb2, ub2, 44)   // p11
    KLOAD(kb2, 56)  ULOAD(ub2, 56)  COMP(kb0, ub0, 48)   // p12
    KLOAD(kb0, 60)  ULOAD(ub0, 60)  COMP(kb1, ub1, 52)   // p13
                                    COMP(kb2, ub2, 56)   // p14
                                    COMP(kb0, ub0, 60)   // p15

    float* __restrict__ yp = y + ((size_t)b * L_SEQ + t0) * D_DIM + d;
    #pragma unroll
    for (int i = 0; i < RT; ++i) yp[(size_t)i * D_DIM] = acc[i];
}

extern "C" void kernel_launch(void* const* d_in, const int* in_sizes, int n_in,
                              void* d_out, int out_size, void* d_ws, size_t ws_size,
                              hipStream_t stream) {
    const float* u  = (const float*)d_in[0];   // (4, 4096, 1024) f32
    const float* ab = (const float*)d_in[1];   // (2048, 64)      f32
    const float* h0 = (const float*)d_in[2];   // (1024,)         f32
    float* y  = (float*)d_out;                 // (4, 4096, 1024) f32
    h2f*   K2 = (h2f*)d_ws;                    // 64 pairs x 1024 ch x 4B = 256 KB

    kinit_kernel<<<dim3(D_DIM), dim3(64), 0, stream>>>(ab, h0, K2);
    conv_kernel<<<dim3(D_DIM / 256, L_SEQ / RT, B_SZ), dim3(256), 0, stream>>>(u, K2, y);
}